// Round 2
// baseline (4617.635 us; speedup 1.0000x reference)
//
#include <hip/hip_runtime.h>
#include <stdint.h>

// LocalContrastiveLoss: exact reproduction of the JAX reference, including
// threefry2x32 PRNG (partitionable mode — verified bit-exact in R0, absmax 0)
// and lax.top_k tie-breaking (lower index wins on equal values).
//
// Shapes: features (B=8, C=256, H=128, W=128) f32; labels (8,128,128) i32.
// Output: single f32 scalar.
//
// R1 structure: 4 kernels.
//   K1 topk:   40 blocks (s,b) x 1024 thr — all 4 classes per pass, int4 labels
//   K2 gather+mu: 544 blocks x 256 thr — 480 gather/normalize + 64 mu blocks
//   K3 loss:   96 blocks x 256 thr — 33 dots per anchor + masked log terms
//   K4 final:  1 block

namespace {

constexpr int Nn = 16384;   // H*W

// ---------------- threefry2x32 (matches jax/_src/prng.py exactly) ----------
__device__ __forceinline__ uint32_t rotl32(uint32_t v, int d) {
  return (v << d) | (v >> (32 - d));
}

__device__ __forceinline__ void threefry2x32(uint32_t k0, uint32_t k1,
                                             uint32_t x0, uint32_t x1,
                                             uint32_t& o0, uint32_t& o1) {
  uint32_t ks2 = k0 ^ k1 ^ 0x1BD11BDAu;
  x0 += k0; x1 += k1;
#define TF_R(d) { x0 += x1; x1 = rotl32(x1, (d)); x1 ^= x0; }
  TF_R(13) TF_R(15) TF_R(26) TF_R(6)
  x0 += k1; x1 += ks2 + 1u;
  TF_R(17) TF_R(29) TF_R(16) TF_R(24)
  x0 += ks2; x1 += k0 + 2u;
  TF_R(13) TF_R(15) TF_R(26) TF_R(6)
  x0 += k0; x1 += k1 + 3u;
  TF_R(17) TF_R(29) TF_R(16) TF_R(24)
  x0 += k1; x1 += ks2 + 4u;
  TF_R(13) TF_R(15) TF_R(26) TF_R(6)
  x0 += ks2; x1 += k0 + 5u;
#undef TF_R
  o0 = x0; o1 = x1;
}

// insert candidate into sorted (descending) top-3 list
__device__ __forceinline__ void ins3(unsigned long long t[3], unsigned long long k) {
  if (k > t[0])      { t[2] = t[1]; t[1] = t[0]; t[0] = k; }
  else if (k > t[1]) { t[2] = t[1]; t[1] = k; }
  else if (k > t[2]) { t[2] = k; }
}

// ---------------- K1: per (key s, image b) top-3 of ALL 4 classes + counts -
// Packed rank key: (uniform_float_bits << 32) | (0xFFFFFFFF - pixel_index).
// float bits ((bits>>9)|0x3f800000) are monotone in the uniform value; the
// complemented index reproduces lax.top_k's lower-index-wins tie rule.
// One threefry per pixel: only the draw at j=(b*4+lab)*N+n can ever matter.
__global__ __launch_bounds__(1024) void topk_kernel(
    const int4* __restrict__ labels4,
    int* __restrict__ idx_buf,
    int* __restrict__ counts) {
  const int g = blockIdx.x;          // 40 = 5*8: s*8 + b
  const int s = g >> 3;
  const int b = g & 7;

  // subkey = jax.random.split(key(42), 5)[s]
  uint32_t sk0, sk1;
  threefry2x32(0u, 42u, 0u, (uint32_t)s, sk0, sk1);

  unsigned long long t[4][3] = {{0ull,0ull,0ull},{0ull,0ull,0ull},
                                {0ull,0ull,0ull},{0ull,0ull,0ull}};
  int cnt0 = 0, cnt1 = 0, cnt2 = 0, cnt3 = 0;

  const int4* row = labels4 + b * (Nn / 4);
  const uint32_t jbase = (uint32_t)(b * 4 * Nn);
#pragma unroll
  for (int j = 0; j < 4; ++j) {
    const int i4 = threadIdx.x + j * 1024;
    const int4 L = row[i4];
    const int la[4] = {L.x, L.y, L.z, L.w};
#pragma unroll
    for (int e = 0; e < 4; ++e) {
      const int lab = la[e];
      const uint32_t n = (uint32_t)(i4 * 4 + e);
      uint32_t r0, r1;
      threefry2x32(sk0, sk1, 0u, jbase + (uint32_t)lab * (uint32_t)Nn + n, r0, r1);
      const uint32_t bits = r0 ^ r1;                 // partitionable 32-bit draw
      const uint32_t fb = (bits >> 9) | 0x3f800000u; // uniform float bits [1,2)
      const unsigned long long key = ((unsigned long long)fb << 32) |
                                     (unsigned long long)(0xFFFFFFFFu - n);
      if (lab == 0) { ins3(t[0], key); ++cnt0; }
      else if (lab == 1) { ins3(t[1], key); ++cnt1; }
      else if (lab == 2) { ins3(t[2], key); ++cnt2; }
      else { ins3(t[3], key); ++cnt3; }
    }
  }

  // wave reduction (64 lanes)
  for (int off = 32; off > 0; off >>= 1) {
#pragma unroll
    for (int c = 0; c < 4; ++c) {
      unsigned long long o0 = __shfl_down(t[c][0], (unsigned)off);
      unsigned long long o1 = __shfl_down(t[c][1], (unsigned)off);
      unsigned long long o2 = __shfl_down(t[c][2], (unsigned)off);
      ins3(t[c], o0); ins3(t[c], o1); ins3(t[c], o2);
    }
    cnt0 += __shfl_down(cnt0, (unsigned)off);
    cnt1 += __shfl_down(cnt1, (unsigned)off);
    cnt2 += __shfl_down(cnt2, (unsigned)off);
    cnt3 += __shfl_down(cnt3, (unsigned)off);
  }

  __shared__ unsigned long long sm[16][4][3];
  __shared__ int sc[16][4];
  const int lane = threadIdx.x & 63;
  const int wave = threadIdx.x >> 6;
  if (lane == 0) {
#pragma unroll
    for (int c = 0; c < 4; ++c) {
      sm[wave][c][0] = t[c][0]; sm[wave][c][1] = t[c][1]; sm[wave][c][2] = t[c][2];
    }
    sc[wave][0] = cnt0; sc[wave][1] = cnt1; sc[wave][2] = cnt2; sc[wave][3] = cnt3;
  }
  __syncthreads();
  if (threadIdx.x < 4) {
    const int c = threadIdx.x;
    unsigned long long f[3] = {sm[0][c][0], sm[0][c][1], sm[0][c][2]};
    int tot = sc[0][c];
    for (int w = 1; w < 16; ++w) {
      ins3(f, sm[w][c][0]); ins3(f, sm[w][c][1]); ins3(f, sm[w][c][2]);
      tot += sc[w][c];
    }
#pragma unroll
    for (int r = 0; r < 3; ++r) {
      // empty slot (key==0): index irrelevant (masked downstream), use 0
      const int n = (f[r] == 0ull) ? 0
                    : (int)(0xFFFFFFFFu - (uint32_t)(f[r] & 0xFFFFFFFFull));
      idx_buf[(g * 4 + c) * 3 + r] = n;   // flat [s][b][c][r]
    }
    if (s == 0) counts[b * 4 + c] = tot;
  }
}

// ---------------- K2: gather+normalize (g<480) | mu vectors (g>=480) -------
__global__ void gather_mu_kernel(const float* __restrict__ feat,
                                 const int* __restrict__ idx_buf,
                                 float* __restrict__ fnorm,
                                 float* __restrict__ mu) {
  const int g = blockIdx.x;          // 544 = 480 gather + 64 mu
  const int ch = threadIdx.x;        // 256 channels
  const int lane = threadIdx.x & 63, wave = threadIdx.x >> 6;
  __shared__ float sr[4][4];
  __shared__ float sr2[4];

  if (g < 480) {
    // gather one sampled pixel, L2-normalize over channels
    const int b = (g / 12) & 7;
    const int n = idx_buf[g];
    const float v = feat[((b << 8) + ch) * Nn + n];
    float ss = v * v;
    for (int off = 32; off > 0; off >>= 1) ss += __shfl_down(ss, (unsigned)off);
    if (lane == 0) sr[wave][0] = ss;
    __syncthreads();
    const float nrm = fmaxf(sqrtf(sr[0][0] + sr[1][0] + sr[2][0] + sr[3][0]), 1e-12f);
    fnorm[g * 256 + ch] = v / nrm;
  } else {
    // mu = unit(mean of 3 normalized sampled vectors)
    // m=0: sample s=0 (part-1 mu1). m=1: sample s=3 (part-2 mu2).
    const int gm = g - 480;          // 64 = 2*8*4: m*32 + b*4 + c
    const int m = gm >> 5;
    const int bc = gm & 31;
    const int b = bc >> 2;
    const int s = m ? 3 : 0;
    const int ib = (s * 32 + bc) * 3;
    float v[3], ss[3];
#pragma unroll
    for (int r = 0; r < 3; ++r) {
      const int n = idx_buf[ib + r];
      v[r] = feat[((b << 8) + ch) * Nn + n];
      ss[r] = v[r] * v[r];
    }
    for (int off = 32; off > 0; off >>= 1) {
#pragma unroll
      for (int r = 0; r < 3; ++r) ss[r] += __shfl_down(ss[r], (unsigned)off);
    }
    if (lane == 0) {
#pragma unroll
      for (int r = 0; r < 3; ++r) sr[wave][r] = ss[r];
    }
    __syncthreads();
    float f = 0.f;
#pragma unroll
    for (int r = 0; r < 3; ++r) {
      const float nrm = fmaxf(sqrtf(sr[0][r] + sr[1][r] + sr[2][r] + sr[3][r]), 1e-12f);
      f += v[r] / nrm;
    }
    f /= 3.0f;
    float s2 = f * f;
    for (int off = 32; off > 0; off >>= 1) s2 += __shfl_down(s2, (unsigned)off);
    if (lane == 0) sr2[wave] = s2;
    __syncthreads();
    const float nrm2 = fmaxf(sqrtf(sr2[0] + sr2[1] + sr2[2] + sr2[3]), 1e-8f);
    mu[gm * 256 + ch] = f / nrm2;
  }
}

// ---------------- K3: per-anchor (b,c,p) loss terms ------------------------
__global__ void loss_kernel(const float* __restrict__ fnorm,
                            const float* __restrict__ mu,
                            const int* __restrict__ counts,
                            float* __restrict__ partials) {
  const int g = blockIdx.x;          // 96 = 8*4*3
  const int b = g / 12;
  const int c = (g % 12) / 3;
  const int p = g % 3;
  const int ch = threadIdx.x;
  const int bc = b * 4 + c;

  const float a1 = fnorm[(bc * 3 + p) * 256 + ch];           // s=0 anchor
  const float a2 = fnorm[((64 + bc) * 3 + p) * 256 + ch];    // s=2 anchor

  float part[33];
  // [0] dot(a1, mu1[b,c])
  part[0] = a1 * mu[bc * 256 + ch];
  // [1..12] dot(a1, neg1[b,e,k])   (s=1)
#pragma unroll
  for (int e = 0; e < 4; ++e)
#pragma unroll
    for (int k = 0; k < 3; ++k)
      part[1 + e * 3 + k] = a1 * fnorm[((32 + b * 4 + e) * 3 + k) * 256 + ch];
  // [13..20] dot(a2, mu2[b2,c])
#pragma unroll
  for (int b2 = 0; b2 < 8; ++b2)
    part[13 + b2] = a2 * mu[(32 + b2 * 4 + c) * 256 + ch];
  // [21..32] dot(a2, neg2[b,e,k])  (s=4)
#pragma unroll
  for (int e = 0; e < 4; ++e)
#pragma unroll
    for (int k = 0; k < 3; ++k)
      part[21 + e * 3 + k] = a2 * fnorm[((128 + b * 4 + e) * 3 + k) * 256 + ch];

  for (int off = 32; off > 0; off >>= 1) {
#pragma unroll
    for (int i = 0; i < 33; ++i) part[i] += __shfl_down(part[i], (unsigned)off);
  }
  __shared__ float red[4][33];
  const int lane = threadIdx.x & 63, wave = threadIdx.x >> 6;
  if (lane == 0) {
#pragma unroll
    for (int i = 0; i < 33; ++i) red[wave][i] = part[i];
  }
  __syncthreads();

  if (threadIdx.x == 0) {
    float d[33];
#pragma unroll
    for (int i = 0; i < 33; ++i) d[i] = red[0][i] + red[1][i] + red[2][i] + red[3][i];

    int cb[4];
    for (int e = 0; e < 4; ++e) cb[e] = counts[b * 4 + e];
    bool has_neg = false;
    for (int e = 0; e < 4; ++e) if (e != c && cb[e] > 0) has_neg = true;
    const bool valid_anchor = (cb[c] >= 3) && has_neg;

    float sn1 = 0.f, sn2 = 0.f;
    for (int e = 0; e < 4; ++e) {
      if (e == c) continue;
      int km = cb[e] < 3 ? cb[e] : 3;
      for (int k = 0; k < km; ++k) {
        sn1 += expf(d[1 + e * 3 + k] * 10.0f);
        sn2 += expf(d[21 + e * 3 + k] * 10.0f);
      }
    }
    float term = 0.f;
    if (valid_anchor) {
      float sp1 = expf(d[0] * 10.0f);
      term -= logf(sp1 / (sp1 + sn1 + 1e-8f));
      for (int b2 = 0; b2 < 8; ++b2) {
        if (b2 == b) continue;
        if (counts[b2 * 4 + c] >= 3) {
          float sp2 = expf(d[13 + b2] * 10.0f);
          term -= logf(sp2 / (sp2 + sn2 + 1e-8f));
        }
      }
    }
    partials[g] = term;
  }
}

// ---------------- K4: final reduce + scale ---------------------------------
__global__ void finalize_kernel(const float* __restrict__ partials,
                                float* __restrict__ out) {
  const int t = threadIdx.x;         // 128 threads
  float v = (t < 96) ? partials[t] : 0.f;
  for (int off = 32; off > 0; off >>= 1) v += __shfl_down(v, (unsigned)off);
  __shared__ float s2[2];
  if ((t & 63) == 0) s2[t >> 6] = v;
  __syncthreads();
  if (t == 0) {
    double total = (double)s2[0] + (double)s2[1];
    out[0] = (float)(0.1 * total / (24.0 + 1e-8));  // LAM*loss/(B*P+EPS)
  }
}

}  // namespace

extern "C" void kernel_launch(void* const* d_in, const int* in_sizes, int n_in,
                              void* d_out, int out_size, void* d_ws, size_t ws_size,
                              hipStream_t stream) {
  const float* feat = (const float*)d_in[0];
  const int* labels = (const int*)d_in[1];
  float* out = (float*)d_out;
  char* ws = (char*)d_ws;

  // workspace layout (bytes):
  //   [0, 1920)            idx_buf: 5*8*4*3 int32 sampled pixel indices
  //   [1920, 2048)         counts : 8*4 int32 class counts
  //   [2048, 493568)       fnorm  : 480*256 f32 normalized sampled vectors
  //   [493568, 559104)     mu     : 2*32*256 f32 unit means
  //   [559104, 559488)     partials: 96 f32 per-anchor loss terms
  int* idx_buf    = (int*)(ws);
  int* counts     = (int*)(ws + 1920);
  float* fnorm    = (float*)(ws + 2048);
  float* mu       = (float*)(ws + 493568);
  float* partials = (float*)(ws + 559104);

  topk_kernel<<<40, 1024, 0, stream>>>((const int4*)labels, idx_buf, counts);
  gather_mu_kernel<<<544, 256, 0, stream>>>(feat, idx_buf, fnorm, mu);
  loss_kernel<<<96, 256, 0, stream>>>(fnorm, mu, counts, partials);
  finalize_kernel<<<1, 128, 0, stream>>>(partials, out);
}

// Round 3
// 201.131 us; speedup vs baseline: 22.9583x; 22.9583x over previous
//
#include <hip/hip_runtime.h>
#include <stdint.h>

// LocalContrastiveLoss: exact reproduction of the JAX reference, including
// threefry2x32 PRNG (partitionable mode — verified bit-exact, absmax 0) and
// lax.top_k tie-breaking (lower index wins on equal values).
//
// Shapes: features (B=8, C=256, H=128, W=128) f32; labels (8,128,128) i32.
// Output: single f32 scalar.
//
// R3 structure (lesson from R2: 1024-thr + per-thread t[4][3] spilled 3 GB to
// scratch — keep per-thread state tiny):
//   K1 topk:   160 blocks (s,b,c) x 256 thr — t[3] only (6 VGPRs), int4
//              label loads, branchless threefry (exec-mask makes conditional
//              threefry cost the same anyway)
//   K2 gather+mu: 544 blocks x 256 thr
//   K3 loss:   96 blocks x 256 thr — 33 dots per anchor + masked log terms
//   K4 final:  1 block

namespace {

constexpr int Nn = 16384;   // H*W

// ---------------- threefry2x32 (matches jax/_src/prng.py exactly) ----------
__device__ __forceinline__ uint32_t rotl32(uint32_t v, int d) {
  return (v << d) | (v >> (32 - d));
}

__device__ __forceinline__ void threefry2x32(uint32_t k0, uint32_t k1,
                                             uint32_t x0, uint32_t x1,
                                             uint32_t& o0, uint32_t& o1) {
  uint32_t ks2 = k0 ^ k1 ^ 0x1BD11BDAu;
  x0 += k0; x1 += k1;
#define TF_R(d) { x0 += x1; x1 = rotl32(x1, (d)); x1 ^= x0; }
  TF_R(13) TF_R(15) TF_R(26) TF_R(6)
  x0 += k1; x1 += ks2 + 1u;
  TF_R(17) TF_R(29) TF_R(16) TF_R(24)
  x0 += ks2; x1 += k0 + 2u;
  TF_R(13) TF_R(15) TF_R(26) TF_R(6)
  x0 += k0; x1 += k1 + 3u;
  TF_R(17) TF_R(29) TF_R(16) TF_R(24)
  x0 += k1; x1 += ks2 + 4u;
  TF_R(13) TF_R(15) TF_R(26) TF_R(6)
  x0 += ks2; x1 += k0 + 5u;
#undef TF_R
  o0 = x0; o1 = x1;
}

// insert candidate into sorted (descending) top-3 list; key==0 never inserts
__device__ __forceinline__ void ins3(unsigned long long t[3], unsigned long long k) {
  if (k > t[0])      { t[2] = t[1]; t[1] = t[0]; t[0] = k; }
  else if (k > t[1]) { t[2] = t[1]; t[1] = k; }
  else if (k > t[2]) { t[2] = k; }
}

// ---------------- K1: per (key s, image b, class c) top-3 + counts ---------
// Packed rank key: (uniform_float_bits << 32) | (0xFFFFFFFF - pixel_index).
// float bits ((bits>>9)|0x3f800000) are monotone in the uniform value; the
// complemented index reproduces lax.top_k's lower-index-wins tie rule.
// Branchless: threefry for every pixel, masked to 0 when label != c (a wave
// pays the hash whenever any lane matches, so this costs nothing extra).
// Per-thread state kept tiny (t[3] = 6 VGPRs) — R2's t[4][3] @1024thr spilled.
__global__ void topk_kernel(const int4* __restrict__ labels4,
                            int* __restrict__ idx_buf,
                            int* __restrict__ counts) {
  const int g = blockIdx.x;          // 160: g = s*32 + b*4 + c
  const int s = g >> 5;
  const int b = (g >> 2) & 7;
  const int c = g & 3;

  // subkey = jax.random.split(key(42), 5)[s]
  uint32_t sk0, sk1;
  threefry2x32(0u, 42u, 0u, (uint32_t)s, sk0, sk1);

  unsigned long long t[3] = {0ull, 0ull, 0ull};
  int cnt = 0;
  const int4* row = labels4 + b * (Nn / 4);
  const uint32_t jbase = (uint32_t)((b * 4 + c) * Nn);
#pragma unroll 4
  for (int it = 0; it < 16; ++it) {
    const int i4 = threadIdx.x + it * 256;
    const int4 L = row[i4];
    const int la[4] = {L.x, L.y, L.z, L.w};
#pragma unroll
    for (int e = 0; e < 4; ++e) {
      const uint32_t n = (uint32_t)(i4 * 4 + e);
      uint32_t r0, r1;
      threefry2x32(sk0, sk1, 0u, jbase + n, r0, r1);
      const uint32_t bits = r0 ^ r1;                 // partitionable 32-bit draw
      const uint32_t fb = (bits >> 9) | 0x3f800000u; // uniform float bits [1,2)
      const bool m = (la[e] == c);
      const unsigned long long key =
          m ? (((unsigned long long)fb << 32) |
               (unsigned long long)(0xFFFFFFFFu - n))
            : 0ull;
      cnt += m ? 1 : 0;
      ins3(t, key);
    }
  }

  // wave (64-lane) reduction
  for (int off = 32; off > 0; off >>= 1) {
    unsigned long long o0 = __shfl_down(t[0], (unsigned)off);
    unsigned long long o1 = __shfl_down(t[1], (unsigned)off);
    unsigned long long o2 = __shfl_down(t[2], (unsigned)off);
    int oc = __shfl_down(cnt, (unsigned)off);
    ins3(t, o0); ins3(t, o1); ins3(t, o2);
    cnt += oc;
  }
  __shared__ unsigned long long sm[4][3];
  __shared__ int sc[4];
  const int lane = threadIdx.x & 63;
  const int wave = threadIdx.x >> 6;
  if (lane == 0) { sm[wave][0] = t[0]; sm[wave][1] = t[1]; sm[wave][2] = t[2]; sc[wave] = cnt; }
  __syncthreads();
  if (threadIdx.x == 0) {
    unsigned long long f[3] = {sm[0][0], sm[0][1], sm[0][2]};
    int tot = sc[0];
    for (int w = 1; w < 4; ++w) {
      ins3(f, sm[w][0]); ins3(f, sm[w][1]); ins3(f, sm[w][2]);
      tot += sc[w];
    }
#pragma unroll
    for (int r = 0; r < 3; ++r) {
      // empty slot (key==0): index irrelevant (masked downstream), use 0
      const int n = (f[r] == 0ull) ? 0
                    : (int)(0xFFFFFFFFu - (uint32_t)(f[r] & 0xFFFFFFFFull));
      idx_buf[g * 3 + r] = n;          // flat [s][b][c][r]
    }
    if (s == 0) counts[b * 4 + c] = tot;
  }
}

// ---------------- K2: gather+normalize (g<480) | mu vectors (g>=480) -------
__global__ void gather_mu_kernel(const float* __restrict__ feat,
                                 const int* __restrict__ idx_buf,
                                 float* __restrict__ fnorm,
                                 float* __restrict__ mu) {
  const int g = blockIdx.x;          // 544 = 480 gather + 64 mu
  const int ch = threadIdx.x;        // 256 channels
  const int lane = threadIdx.x & 63, wave = threadIdx.x >> 6;
  __shared__ float sr[4][4];
  __shared__ float sr2[4];

  if (g < 480) {
    // gather one sampled pixel, L2-normalize over channels
    const int b = (g / 12) & 7;
    const int n = idx_buf[g];
    const float v = feat[((b << 8) + ch) * Nn + n];
    float ss = v * v;
    for (int off = 32; off > 0; off >>= 1) ss += __shfl_down(ss, (unsigned)off);
    if (lane == 0) sr[wave][0] = ss;
    __syncthreads();
    const float nrm = fmaxf(sqrtf(sr[0][0] + sr[1][0] + sr[2][0] + sr[3][0]), 1e-12f);
    fnorm[g * 256 + ch] = v / nrm;
  } else {
    // mu = unit(mean of 3 normalized sampled vectors)
    // m=0: sample s=0 (part-1 mu1). m=1: sample s=3 (part-2 mu2).
    const int gm = g - 480;          // 64 = 2*8*4: m*32 + b*4 + c
    const int m = gm >> 5;
    const int bc = gm & 31;
    const int b = bc >> 2;
    const int s = m ? 3 : 0;
    const int ib = (s * 32 + bc) * 3;
    float v[3], ss[3];
#pragma unroll
    for (int r = 0; r < 3; ++r) {
      const int n = idx_buf[ib + r];
      v[r] = feat[((b << 8) + ch) * Nn + n];
      ss[r] = v[r] * v[r];
    }
    for (int off = 32; off > 0; off >>= 1) {
#pragma unroll
      for (int r = 0; r < 3; ++r) ss[r] += __shfl_down(ss[r], (unsigned)off);
    }
    if (lane == 0) {
#pragma unroll
      for (int r = 0; r < 3; ++r) sr[wave][r] = ss[r];
    }
    __syncthreads();
    float f = 0.f;
#pragma unroll
    for (int r = 0; r < 3; ++r) {
      const float nrm = fmaxf(sqrtf(sr[0][r] + sr[1][r] + sr[2][r] + sr[3][r]), 1e-12f);
      f += v[r] / nrm;
    }
    f /= 3.0f;
    float s2 = f * f;
    for (int off = 32; off > 0; off >>= 1) s2 += __shfl_down(s2, (unsigned)off);
    if (lane == 0) sr2[wave] = s2;
    __syncthreads();
    const float nrm2 = fmaxf(sqrtf(sr2[0] + sr2[1] + sr2[2] + sr2[3]), 1e-8f);
    mu[gm * 256 + ch] = f / nrm2;
  }
}

// ---------------- K3: per-anchor (b,c,p) loss terms ------------------------
__global__ void loss_kernel(const float* __restrict__ fnorm,
                            const float* __restrict__ mu,
                            const int* __restrict__ counts,
                            float* __restrict__ partials) {
  const int g = blockIdx.x;          // 96 = 8*4*3
  const int b = g / 12;
  const int c = (g % 12) / 3;
  const int p = g % 3;
  const int ch = threadIdx.x;
  const int bc = b * 4 + c;

  const float a1 = fnorm[(bc * 3 + p) * 256 + ch];           // s=0 anchor
  const float a2 = fnorm[((64 + bc) * 3 + p) * 256 + ch];    // s=2 anchor

  float part[33];
  // [0] dot(a1, mu1[b,c])
  part[0] = a1 * mu[bc * 256 + ch];
  // [1..12] dot(a1, neg1[b,e,k])   (s=1)
#pragma unroll
  for (int e = 0; e < 4; ++e)
#pragma unroll
    for (int k = 0; k < 3; ++k)
      part[1 + e * 3 + k] = a1 * fnorm[((32 + b * 4 + e) * 3 + k) * 256 + ch];
  // [13..20] dot(a2, mu2[b2,c])
#pragma unroll
  for (int b2 = 0; b2 < 8; ++b2)
    part[13 + b2] = a2 * mu[(32 + b2 * 4 + c) * 256 + ch];
  // [21..32] dot(a2, neg2[b,e,k])  (s=4)
#pragma unroll
  for (int e = 0; e < 4; ++e)
#pragma unroll
    for (int k = 0; k < 3; ++k)
      part[21 + e * 3 + k] = a2 * fnorm[((128 + b * 4 + e) * 3 + k) * 256 + ch];

  for (int off = 32; off > 0; off >>= 1) {
#pragma unroll
    for (int i = 0; i < 33; ++i) part[i] += __shfl_down(part[i], (unsigned)off);
  }
  __shared__ float red[4][33];
  const int lane = threadIdx.x & 63, wave = threadIdx.x >> 6;
  if (lane == 0) {
#pragma unroll
    for (int i = 0; i < 33; ++i) red[wave][i] = part[i];
  }
  __syncthreads();

  if (threadIdx.x == 0) {
    float d[33];
#pragma unroll
    for (int i = 0; i < 33; ++i) d[i] = red[0][i] + red[1][i] + red[2][i] + red[3][i];

    int cb[4];
    for (int e = 0; e < 4; ++e) cb[e] = counts[b * 4 + e];
    bool has_neg = false;
    for (int e = 0; e < 4; ++e) if (e != c && cb[e] > 0) has_neg = true;
    const bool valid_anchor = (cb[c] >= 3) && has_neg;

    float sn1 = 0.f, sn2 = 0.f;
    for (int e = 0; e < 4; ++e) {
      if (e == c) continue;
      int km = cb[e] < 3 ? cb[e] : 3;
      for (int k = 0; k < km; ++k) {
        sn1 += expf(d[1 + e * 3 + k] * 10.0f);
        sn2 += expf(d[21 + e * 3 + k] * 10.0f);
      }
    }
    float term = 0.f;
    if (valid_anchor) {
      float sp1 = expf(d[0] * 10.0f);
      term -= logf(sp1 / (sp1 + sn1 + 1e-8f));
      for (int b2 = 0; b2 < 8; ++b2) {
        if (b2 == b) continue;
        if (counts[b2 * 4 + c] >= 3) {
          float sp2 = expf(d[13 + b2] * 10.0f);
          term -= logf(sp2 / (sp2 + sn2 + 1e-8f));
        }
      }
    }
    partials[g] = term;
  }
}

// ---------------- K4: final reduce + scale ---------------------------------
__global__ void finalize_kernel(const float* __restrict__ partials,
                                float* __restrict__ out) {
  const int t = threadIdx.x;         // 128 threads
  float v = (t < 96) ? partials[t] : 0.f;
  for (int off = 32; off > 0; off >>= 1) v += __shfl_down(v, (unsigned)off);
  __shared__ float s2[2];
  if ((t & 63) == 0) s2[t >> 6] = v;
  __syncthreads();
  if (t == 0) {
    double total = (double)s2[0] + (double)s2[1];
    out[0] = (float)(0.1 * total / (24.0 + 1e-8));  // LAM*loss/(B*P+EPS)
  }
}

}  // namespace

extern "C" void kernel_launch(void* const* d_in, const int* in_sizes, int n_in,
                              void* d_out, int out_size, void* d_ws, size_t ws_size,
                              hipStream_t stream) {
  const float* feat = (const float*)d_in[0];
  const int* labels = (const int*)d_in[1];
  float* out = (float*)d_out;
  char* ws = (char*)d_ws;

  // workspace layout (bytes):
  //   [0, 1920)            idx_buf: 5*8*4*3 int32 sampled pixel indices
  //   [1920, 2048)         counts : 8*4 int32 class counts
  //   [2048, 493568)       fnorm  : 480*256 f32 normalized sampled vectors
  //   [493568, 559104)     mu     : 2*32*256 f32 unit means
  //   [559104, 559488)     partials: 96 f32 per-anchor loss terms
  int* idx_buf    = (int*)(ws);
  int* counts     = (int*)(ws + 1920);
  float* fnorm    = (float*)(ws + 2048);
  float* mu       = (float*)(ws + 493568);
  float* partials = (float*)(ws + 559104);

  topk_kernel<<<160, 256, 0, stream>>>((const int4*)labels, idx_buf, counts);
  gather_mu_kernel<<<544, 256, 0, stream>>>(feat, idx_buf, fnorm, mu);
  loss_kernel<<<96, 256, 0, stream>>>(fnorm, mu, counts, partials);
  finalize_kernel<<<1, 128, 0, stream>>>(partials, out);
}

// Round 4
// 195.948 us; speedup vs baseline: 23.5656x; 1.0265x over previous
//
#include <hip/hip_runtime.h>
#include <stdint.h>

// LocalContrastiveLoss: exact reproduction of the JAX reference, including
// threefry2x32 PRNG (partitionable mode — verified bit-exact, absmax 0) and
// lax.top_k tie-breaking (lower index wins on equal values).
//
// Shapes: features (B=8, C=256, H=128, W=128) f32; labels (8,128,128) i32.
// Output: single f32 scalar.
//
// R4 structure: 2 kernels (timed window is dominated by ~170 µs of harness
// reset traffic; minimize launches + dependency gaps).
//   K1 topk+gather: 160 blocks (s,b,c) x 512 thr — top-3 + counts, then
//      gather + L2-normalize the block's own 3 sampled vectors. Zeroes the
//      loss accumulator/ticket (ws is re-poisoned 0xAA before every call).
//   K2 loss+final: 96 blocks (b,c,p) x 256 thr — 42-slot reduction computing
//      mu inline (dot(a,unit(mean v)) = (a·Σv)/3 / max(‖Σv‖/3,eps)), masked
//      log terms, atomicAdd + ticket; last block writes the scalar.

namespace {

constexpr int Nn = 16384;   // H*W

// ---------------- threefry2x32 (matches jax/_src/prng.py exactly) ----------
__device__ __forceinline__ uint32_t rotl32(uint32_t v, int d) {
  return (v << d) | (v >> (32 - d));
}

__device__ __forceinline__ void threefry2x32(uint32_t k0, uint32_t k1,
                                             uint32_t x0, uint32_t x1,
                                             uint32_t& o0, uint32_t& o1) {
  uint32_t ks2 = k0 ^ k1 ^ 0x1BD11BDAu;
  x0 += k0; x1 += k1;
#define TF_R(d) { x0 += x1; x1 = rotl32(x1, (d)); x1 ^= x0; }
  TF_R(13) TF_R(15) TF_R(26) TF_R(6)
  x0 += k1; x1 += ks2 + 1u;
  TF_R(17) TF_R(29) TF_R(16) TF_R(24)
  x0 += ks2; x1 += k0 + 2u;
  TF_R(13) TF_R(15) TF_R(26) TF_R(6)
  x0 += k0; x1 += k1 + 3u;
  TF_R(17) TF_R(29) TF_R(16) TF_R(24)
  x0 += k1; x1 += ks2 + 4u;
  TF_R(13) TF_R(15) TF_R(26) TF_R(6)
  x0 += ks2; x1 += k0 + 5u;
#undef TF_R
  o0 = x0; o1 = x1;
}

// insert candidate into sorted (descending) top-3 list; key==0 never inserts
__device__ __forceinline__ void ins3(unsigned long long t[3], unsigned long long k) {
  if (k > t[0])      { t[2] = t[1]; t[1] = t[0]; t[0] = k; }
  else if (k > t[1]) { t[2] = t[1]; t[1] = k; }
  else if (k > t[2]) { t[2] = k; }
}

// ---------------- K1: top-3 + counts + fused gather/normalize --------------
// Packed rank key: (uniform_float_bits << 32) | (0xFFFFFFFF - pixel_index).
// float bits ((bits>>9)|0x3f800000) are monotone in the uniform value; the
// complemented index reproduces lax.top_k's lower-index-wins tie rule.
// Branchless threefry (exec-mask makes the conditional cost the same).
__global__ void topk_gather_kernel(const int4* __restrict__ labels4,
                                   const float* __restrict__ feat,
                                   int* __restrict__ counts,
                                   float* __restrict__ fnorm,
                                   float* __restrict__ acc,
                                   int* __restrict__ ticket) {
  const int g = blockIdx.x;          // 160: g = s*32 + b*4 + c
  const int s = g >> 5;
  const int b = (g >> 2) & 7;
  const int c = g & 3;

  if (g == 0 && threadIdx.x == 0) { acc[0] = 0.f; ticket[0] = 0; }

  // subkey = jax.random.split(key(42), 5)[s]
  uint32_t sk0, sk1;
  threefry2x32(0u, 42u, 0u, (uint32_t)s, sk0, sk1);

  unsigned long long t[3] = {0ull, 0ull, 0ull};
  int cnt = 0;
  const int4* row = labels4 + b * (Nn / 4);
  const uint32_t jbase = (uint32_t)((b * 4 + c) * Nn);
#pragma unroll 4
  for (int it = 0; it < 8; ++it) {           // 512 thr x 8 = 4096 int4
    const int i4 = threadIdx.x + it * 512;
    const int4 L = row[i4];
    const int la[4] = {L.x, L.y, L.z, L.w};
#pragma unroll
    for (int e = 0; e < 4; ++e) {
      const uint32_t n = (uint32_t)(i4 * 4 + e);
      uint32_t r0, r1;
      threefry2x32(sk0, sk1, 0u, jbase + n, r0, r1);
      const uint32_t bits = r0 ^ r1;                 // partitionable 32-bit draw
      const uint32_t fb = (bits >> 9) | 0x3f800000u; // uniform float bits [1,2)
      const bool m = (la[e] == c);
      const unsigned long long key =
          m ? (((unsigned long long)fb << 32) |
               (unsigned long long)(0xFFFFFFFFu - n))
            : 0ull;
      cnt += m ? 1 : 0;
      ins3(t, key);
    }
  }

  // wave (64-lane) reduction, then 8-wave merge
  for (int off = 32; off > 0; off >>= 1) {
    unsigned long long o0 = __shfl_down(t[0], (unsigned)off);
    unsigned long long o1 = __shfl_down(t[1], (unsigned)off);
    unsigned long long o2 = __shfl_down(t[2], (unsigned)off);
    int oc = __shfl_down(cnt, (unsigned)off);
    ins3(t, o0); ins3(t, o1); ins3(t, o2);
    cnt += oc;
  }
  __shared__ unsigned long long sm[8][3];
  __shared__ int sc[8];
  __shared__ int sidx[3];
  __shared__ float sr[4][3];
  const int lane = threadIdx.x & 63;
  const int wave = threadIdx.x >> 6;
  if (lane == 0) { sm[wave][0] = t[0]; sm[wave][1] = t[1]; sm[wave][2] = t[2]; sc[wave] = cnt; }
  __syncthreads();
  if (threadIdx.x == 0) {
    unsigned long long f[3] = {sm[0][0], sm[0][1], sm[0][2]};
    int tot = sc[0];
    for (int w = 1; w < 8; ++w) {
      ins3(f, sm[w][0]); ins3(f, sm[w][1]); ins3(f, sm[w][2]);
      tot += sc[w];
    }
#pragma unroll
    for (int r = 0; r < 3; ++r) {
      // empty slot (key==0): index irrelevant (masked downstream), use 0
      sidx[r] = (f[r] == 0ull) ? 0
                : (int)(0xFFFFFFFFu - (uint32_t)(f[r] & 0xFFFFFFFFull));
    }
    if (s == 0) counts[b * 4 + c] = tot;
  }
  __syncthreads();

  // fused gather + per-pixel L2 normalize (threads 0..255; waves 0..3)
  float v[3];
  if (threadIdx.x < 256) {
    const int ch = threadIdx.x;
    float ss[3];
#pragma unroll
    for (int r = 0; r < 3; ++r) {
      v[r] = feat[((b << 8) + ch) * Nn + sidx[r]];
      ss[r] = v[r] * v[r];
    }
    for (int off = 32; off > 0; off >>= 1) {
#pragma unroll
      for (int r = 0; r < 3; ++r) ss[r] += __shfl_down(ss[r], (unsigned)off);
    }
    if (lane == 0) {
#pragma unroll
      for (int r = 0; r < 3; ++r) sr[wave][r] = ss[r];
    }
  }
  __syncthreads();
  if (threadIdx.x < 256) {
    const int ch = threadIdx.x;
#pragma unroll
    for (int r = 0; r < 3; ++r) {
      const float nrm = fmaxf(sqrtf(sr[0][r] + sr[1][r] + sr[2][r] + sr[3][r]), 1e-12f);
      fnorm[(g * 3 + r) * 256 + ch] = v[r] / nrm;
    }
  }
}

// ---------------- K2: loss terms + mu inline + atomic finalize -------------
// fnorm layout: [(s*32 + b*4 + c)*3 + r]*256 + ch,  s: 0=pos1, 1=neg1,
// 2=pos2-anchors, 3=mu2-source, 4=neg2.
__global__ void loss_kernel(const float* __restrict__ fnorm,
                            const int* __restrict__ counts,
                            float* __restrict__ acc,
                            int* __restrict__ ticket,
                            float* __restrict__ out) {
  const int g = blockIdx.x;          // 96 = 8*4*3
  const int b = g / 12;
  const int c = (g % 12) / 3;
  const int p = g % 3;
  const int ch = threadIdx.x;
  const int bc = b * 4 + c;

  const float a1 = fnorm[(bc * 3 + p) * 256 + ch];           // s=0 anchor
  const float a2 = fnorm[((64 + bc) * 3 + p) * 256 + ch];    // s=2 anchor

  // f1sum = sum of the 3 normalized s=0 vectors of (b,c)
  const float f1 = fnorm[(bc * 3 + 0) * 256 + ch] +
                   fnorm[(bc * 3 + 1) * 256 + ch] +
                   fnorm[(bc * 3 + 2) * 256 + ch];

  float part[42];
  part[0] = a1 * f1;                  // a1 . f1sum
  part[1] = f1 * f1;                  // ||f1sum||^2
  // [2..13] dot(a1, neg1[b,e,k])   (s=1)
#pragma unroll
  for (int e = 0; e < 4; ++e)
#pragma unroll
    for (int k = 0; k < 3; ++k)
      part[2 + e * 3 + k] = a1 * fnorm[((32 + b * 4 + e) * 3 + k) * 256 + ch];
  // [14..29] per b2: a2 . f2sum[b2], ||f2sum[b2]||^2   (s=3)
#pragma unroll
  for (int b2 = 0; b2 < 8; ++b2) {
    const int ib = (96 + b2 * 4 + c) * 3;
    const float f2 = fnorm[(ib + 0) * 256 + ch] +
                     fnorm[(ib + 1) * 256 + ch] +
                     fnorm[(ib + 2) * 256 + ch];
    part[14 + 2 * b2]     = a2 * f2;
    part[14 + 2 * b2 + 1] = f2 * f2;
  }
  // [30..41] dot(a2, neg2[b,e,k])  (s=4)
#pragma unroll
  for (int e = 0; e < 4; ++e)
#pragma unroll
    for (int k = 0; k < 3; ++k)
      part[30 + e * 3 + k] = a2 * fnorm[((128 + b * 4 + e) * 3 + k) * 256 + ch];

  for (int off = 32; off > 0; off >>= 1) {
#pragma unroll
    for (int i = 0; i < 42; ++i) part[i] += __shfl_down(part[i], (unsigned)off);
  }
  __shared__ float red[4][42];
  const int lane = threadIdx.x & 63, wave = threadIdx.x >> 6;
  if (lane == 0) {
#pragma unroll
    for (int i = 0; i < 42; ++i) red[wave][i] = part[i];
  }
  __syncthreads();

  if (threadIdx.x == 0) {
    float d[42];
#pragma unroll
    for (int i = 0; i < 42; ++i) d[i] = red[0][i] + red[1][i] + red[2][i] + red[3][i];

    int cb[4];
    for (int e = 0; e < 4; ++e) cb[e] = counts[b * 4 + e];
    bool has_neg = false;
    for (int e = 0; e < 4; ++e) if (e != c && cb[e] > 0) has_neg = true;
    const bool valid_anchor = (cb[c] >= 3) && has_neg;

    float sn1 = 0.f, sn2 = 0.f;
    for (int e = 0; e < 4; ++e) {
      if (e == c) continue;
      int km = cb[e] < 3 ? cb[e] : 3;
      for (int k = 0; k < km; ++k) {
        sn1 += expf(d[2 + e * 3 + k] * 10.0f);
        sn2 += expf(d[30 + e * 3 + k] * 10.0f);
      }
    }
    float term = 0.f;
    if (valid_anchor) {
      // dot(a1, mu1) = (a1.f1sum)/3 / max(||f1sum||/3, eps)
      const float d0 = (d[0] / 3.0f) / fmaxf(sqrtf(d[1]) / 3.0f, 1e-8f);
      const float sp1 = expf(d0 * 10.0f);
      term -= logf(sp1 / (sp1 + sn1 + 1e-8f));
      for (int b2 = 0; b2 < 8; ++b2) {
        if (b2 == b) continue;
        if (counts[b2 * 4 + c] >= 3) {
          const float d2 = (d[14 + 2 * b2] / 3.0f) /
                           fmaxf(sqrtf(d[14 + 2 * b2 + 1]) / 3.0f, 1e-8f);
          const float sp2 = expf(d2 * 10.0f);
          term -= logf(sp2 / (sp2 + sn2 + 1e-8f));
        }
      }
    }
    atomicAdd(acc, term);
    __threadfence();
    const int old = atomicAdd(ticket, 1);
    if (old == 95) {
      const float total = atomicAdd(acc, 0.0f);   // coherent read-after-fence
      out[0] = (float)(0.1 * (double)total / (24.0 + 1e-8));  // LAM*loss/(B*P+EPS)
    }
  }
}

}  // namespace

extern "C" void kernel_launch(void* const* d_in, const int* in_sizes, int n_in,
                              void* d_out, int out_size, void* d_ws, size_t ws_size,
                              hipStream_t stream) {
  const float* feat = (const float*)d_in[0];
  const int* labels = (const int*)d_in[1];
  float* out = (float*)d_out;
  char* ws = (char*)d_ws;

  // workspace layout (bytes):
  //   [0, 128)             counts : 8*4 int32 class counts
  //   [1024, 492544)       fnorm  : 480*256 f32 normalized sampled vectors
  //   [492544, 492548)     acc    : f32 loss accumulator
  //   [492548, 492552)     ticket : int32 completion counter
  int* counts  = (int*)(ws);
  float* fnorm = (float*)(ws + 1024);
  float* acc   = (float*)(ws + 492544);
  int* ticket  = (int*)(ws + 492548);

  topk_gather_kernel<<<160, 512, 0, stream>>>((const int4*)labels, feat,
                                              counts, fnorm, acc, ticket);
  loss_kernel<<<96, 256, 0, stream>>>(fnorm, counts, acc, ticket, out);
}